// Round 5
// baseline (201.695 us; speedup 1.0000x reference)
//
#include <hip/hip_runtime.h>

// Haar DWT2: x (8,64,512,512) fp32 -> (ll,lh,hl,hh) each (8,64,256,256),
// concatenated flat in d_out. Memory-bound.
//
// Wave-contiguous variant: lane j loads ONE contiguous float4 from row 2i and
// one from row 2i+1 (each load instruction = contiguous 1KB across the wave),
// computes 2 output columns (float2 per subband), then adjacent lane pairs
// exchange float2s via shfl_xor(1): even lanes assemble & store float4 LL/HL,
// odd lanes LH/HH. Stores = two contiguous 512B bursts per instruction.
// Same HBM bytes, half the read transactions vs the 32B-stride version.

typedef float v4f __attribute__((ext_vector_type(4)));
typedef float v2f __attribute__((ext_vector_type(2)));

__device__ __forceinline__ v2f shfl_xor1_f2(v2f v) {
    union { v2f f; unsigned long long u; } c;
    c.f = v;
    c.u = __shfl_xor((unsigned long long)c.u, 1, 64);
    return c.f;
}

__device__ __forceinline__ void dwt_wave_item(const float* __restrict__ x,
                                              float* __restrict__ oll,
                                              float* __restrict__ olh,
                                              float* __restrict__ ohl,
                                              float* __restrict__ ohh,
                                              int wi, int lane)
{
    // wave item: plane (9b) | out_row i (8b) | row-half h (1b)
    int plane = wi >> 9;
    int rem   = wi & 511;
    int i     = rem >> 1;
    int h     = rem & 1;

    long long in0 = (long long)plane * 262144 + (i << 10) + (h << 8) + (lane << 2);
    v4f r0 = __builtin_nontemporal_load(reinterpret_cast<const v4f*>(x + in0));
    v4f r1 = __builtin_nontemporal_load(reinterpret_cast<const v4f*>(x + in0 + 512));

    v2f ll, lh, hl, hh;
    {
        float s0 = r0.x + r0.y, d0 = r0.x - r0.y;
        float s1 = r1.x + r1.y, d1 = r1.x - r1.y;
        ll.x = (s0 + s1) * 0.5f; lh.x = (s0 - s1) * 0.5f;
        hl.x = (d0 + d1) * 0.5f; hh.x = (d0 - d1) * 0.5f;
    }
    {
        float s0 = r0.z + r0.w, d0 = r0.z - r0.w;
        float s1 = r1.z + r1.w, d1 = r1.z - r1.w;
        ll.y = (s0 + s1) * 0.5f; lh.y = (s0 - s1) * 0.5f;
        hl.y = (d0 + d1) * 0.5f; hh.y = (d0 - d1) * 0.5f;
    }

    // pair exchange: even lane needs partner's ll/hl, odd needs partner's lh/hh
    v2f pll = shfl_xor1_f2(ll);
    v2f plh = shfl_xor1_f2(lh);
    v2f phl = shfl_xor1_f2(hl);
    v2f phh = shfl_xor1_f2(hh);

    bool odd = (lane & 1) != 0;
    v4f s0v, s1v;
    s0v.x = odd ? plh.x : ll.x;  s0v.y = odd ? plh.y : ll.y;
    s0v.z = odd ? lh.x  : pll.x; s0v.w = odd ? lh.y  : pll.y;
    s1v.x = odd ? phh.x : hl.x;  s1v.y = odd ? phh.y : hl.y;
    s1v.z = odd ? hh.x  : phl.x; s1v.w = odd ? hh.y  : phl.y;

    float* q0 = odd ? olh : oll;
    float* q1 = odd ? ohh : ohl;

    long long o = (long long)plane * 65536 + (i << 8) + (h << 7) + ((lane & ~1) << 1);
    __builtin_nontemporal_store(s0v, reinterpret_cast<v4f*>(q0 + o));
    __builtin_nontemporal_store(s1v, reinterpret_cast<v4f*>(q1 + o));
}

__global__ __launch_bounds__(256) void dwt2_haar_kernel(
    const float* __restrict__ x, float* __restrict__ out, int n_wave_items)
{
    const long long OUT_SZ = 512LL * 65536LL;

    float* __restrict__ oll = out;
    float* __restrict__ olh = out + OUT_SZ;
    float* __restrict__ ohl = out + 2 * OUT_SZ;
    float* __restrict__ ohh = out + 3 * OUT_SZ;

    int tid  = blockIdx.x * blockDim.x + threadIdx.x;
    int w    = tid >> 6;
    int lane = tid & 63;
    int nw   = (gridDim.x * blockDim.x) >> 6;   // total waves = 8192

    // n_wave_items = 262,144 -> exactly 32 items/wave; 2-way unroll for MLP.
    int wi = w;
    for (; wi + nw < n_wave_items; wi += 2 * nw) {
        dwt_wave_item(x, oll, olh, ohl, ohh, wi, lane);
        dwt_wave_item(x, oll, olh, ohl, ohh, wi + nw, lane);
    }
    for (; wi < n_wave_items; wi += nw) {
        dwt_wave_item(x, oll, olh, ohl, ohh, wi, lane);
    }
}

extern "C" void kernel_launch(void* const* d_in, const int* in_sizes, int n_in,
                              void* d_out, int out_size, void* d_ws, size_t ws_size,
                              hipStream_t stream) {
    const float* x = (const float*)d_in[0];
    float* out = (float*)d_out;

    const int n_wave_items = 512 * 256 * 2;  // 262,144
    const int block = 256;
    const int grid = 2048;

    dwt2_haar_kernel<<<grid, block, 0, stream>>>(x, out, n_wave_items);
}